// Round 3
// baseline (222.341 us; speedup 1.0000x reference)
//
#include <hip/hip_runtime.h>
#include <hip/hip_bf16.h>

#define N_TOT 16384
#define B_HALF 8192
#define D 256
#define BN 64
#define NSPLIT 8
#define COLS_PER_SPLIT (N_TOT / NSPLIT)   // 2048
#define NTILES (COLS_PER_SPLIT / BN)      // 32
#define BM 256                            // rows per block = 4 waves * 64

#define LOG2E 1.4426950408889634f
#define LN2   0.6931471805599453f

typedef short bf16x8 __attribute__((ext_vector_type(8)));
typedef float f32x4 __attribute__((ext_vector_type(4)));

__device__ __forceinline__ float fexp2(float x) {
#if __has_builtin(__builtin_amdgcn_exp2f)
    return __builtin_amdgcn_exp2f(x);
#else
    return __expf(x * LN2);
#endif
}

__device__ __forceinline__ ushort f2bf(float x) {
    uint32_t u = __float_as_uint(x);
    uint32_t r = u + 0x7FFFu + ((u >> 16) & 1u);   // RNE; inputs finite
    return (ushort)(r >> 16);
}

// ---------------- stage 1: fp32 -> prescaled bf16 concat ----------------
// zbs = z * sqrt(scale * log2e)  so that  zbs_i . zbs_j = log2-domain logit
__global__ void convert_kernel(const float* __restrict__ z1,
                               const float* __restrict__ z2,
                               const float* __restrict__ lsp,
                               ushort* __restrict__ zb) {
    const float scale = fminf(__expf(lsp[0]), 100.0f);
    const float s = __fsqrt_rn(scale * LOG2E);
    int idx = blockIdx.x * blockDim.x + threadIdx.x;   // over N_TOT*D/4
    const int total4 = N_TOT * D / 4;
    if (idx >= total4) return;
    int i = idx * 4;
    const int half_elems = B_HALF * D;
    const float* src = (i < half_elems) ? (z1 + i) : (z2 + (i - half_elems));
    float4 f = *reinterpret_cast<const float4*>(src);
    ushort4 o;
    o.x = f2bf(f.x * s); o.y = f2bf(f.y * s); o.z = f2bf(f.z * s); o.w = f2bf(f.w * s);
    *reinterpret_cast<ushort4*>(zb + i) = o;
}

// ---------------- stage 1b: exact fp32 target logits ----------------
__global__ void target_kernel(const float* __restrict__ z1,
                              const float* __restrict__ z2,
                              const float* __restrict__ lsp,
                              float* __restrict__ tnat) {
    const int r    = blockIdx.x * 4 + (threadIdx.x >> 6);
    const int lane = threadIdx.x & 63;
    const float* zr = (r < B_HALF) ? (z1 + (size_t)r * D) : (z2 + (size_t)(r - B_HALF) * D);
    const float* zp = (r < B_HALF) ? (z2 + (size_t)r * D) : (z1 + (size_t)(r - B_HALF) * D);
    float4 a = *reinterpret_cast<const float4*>(zr + lane * 4);
    float4 b = *reinterpret_cast<const float4*>(zp + lane * 4);
    float d = a.x * b.x + a.y * b.y + a.z * b.z + a.w * b.w;
#pragma unroll
    for (int off = 1; off < 64; off <<= 1) d += __shfl_xor(d, off);
    if (lane == 0) {
        const float scale = fminf(__expf(lsp[0]), 100.0f);
        tnat[r] = scale * d;
    }
}

// ---------------- epilogue helper ----------------
template<bool MASKD>
__device__ __forceinline__ void epilogue(const f32x4 (&acc)[4][4],
                                         float (&m2)[16], float (&l2)[16],
                                         int qrow0, int crow0, int g, int lg) {
#pragma unroll
    for (int mi = 0; mi < 4; ++mi) {
#pragma unroll
        for (int j = 0; j < 4; ++j) {
            const int slot = mi * 4 + j;
            float v0 = acc[mi][0][j], v1 = acc[mi][1][j];
            float v2 = acc[mi][2][j], v3 = acc[mi][3][j];
            if (MASKD) {
                const int r  = qrow0 + mi * 16 + g * 4 + j;
                const int c0 = crow0 + lg;
                if (c0      == r) v0 = -1e30f;
                if (c0 + 16 == r) v1 = -1e30f;
                if (c0 + 32 == r) v2 = -1e30f;
                if (c0 + 48 == r) v3 = -1e30f;
            }
            const float m_old = m2[slot];
            float m_new = fmaxf(fmaxf(fmaxf(v0, v1), fmaxf(v2, v3)), m_old);
            float lr = l2[slot] * fexp2(m_old - m_new);
            lr += fexp2(v0 - m_new);
            lr += fexp2(v1 - m_new);
            lr += fexp2(v2 - m_new);
            lr += fexp2(v3 - m_new);
            m2[slot] = m_new;
            l2[slot] = lr;
        }
    }
}

// ---------------- stage 2: flash-style LSE sweep, M-rep=4, dbuf LDS ----------------
__global__ __launch_bounds__(256, 2)
void infonce_main(const ushort* __restrict__ zbs,
                  float* __restrict__ part) {
    __shared__ ushort ks[2][BN * D];   // 2 x 32 KB, linear layout (source pre-swizzled)

    const int tid  = threadIdx.x;
    const int wid  = tid >> 6;
    const int lane = tid & 63;
    const int g    = lane >> 4;     // 0..3
    const int lg   = lane & 15;     // 0..15
    const int swr  = lg & 7;        // read-side XOR key
    const int qrow0   = blockIdx.x * BM + wid * 64;
    const int split   = blockIdx.y;
    const int colbase = split * COLS_PER_SPLIT;

    // A fragments: 4 M-frags x 8 K-frags, register-resident all sweep (128 VGPR)
    bf16x8 afrag[4][8];
#pragma unroll
    for (int mi = 0; mi < 4; ++mi) {
        const ushort* ap = zbs + (size_t)(qrow0 + mi * 16 + lg) * D + g * 8;
#pragma unroll
        for (int kk = 0; kk < 8; ++kk)
            afrag[mi][kk] = *reinterpret_cast<const bf16x8*>(ap + kk * 32);
    }

    float m2[16], l2[16];
#pragma unroll
    for (int s = 0; s < 16; ++s) { m2[s] = -1e30f; l2[s] = 0.0f; }

    // staging thread-constants (source pre-swizzle; LDS dest linear)
    const int rrb  = tid >> 5;                 // 0..7
    const int gsrc = (tid & 31) ^ rrb;         // pre-swizzled source granule
    const ushort* src0 = zbs + (size_t)rrb * D + gsrc * 8;

#define STAGE(buf, t)                                                              \
    {                                                                              \
        const ushort* srcT = src0 + (size_t)(colbase + (t) * BN) * D;              \
        _Pragma("unroll")                                                          \
        for (int it = 0; it < 8; ++it)                                             \
            __builtin_amdgcn_global_load_lds(                                      \
                (const __attribute__((address_space(1))) void*)(srcT + it * 8 * D),\
                (__attribute__((address_space(3))) void*)&ks[buf][it * 2048 + wid * 512], \
                16, 0, 0);                                                         \
    }

    STAGE(0, 0);
    __syncthreads();
    int cur = 0;

    for (int t = 0; t < NTILES; ++t) {
        if (t + 1 < NTILES) STAGE(cur ^ 1, t + 1);   // prefetch next tile (other buffer)

        f32x4 acc[4][4];
#pragma unroll
        for (int mi = 0; mi < 4; ++mi)
#pragma unroll
            for (int n = 0; n < 4; ++n) acc[mi][n] = (f32x4){0.f, 0.f, 0.f, 0.f};

        const ushort* kbase = &ks[cur][0];
#pragma unroll
        for (int kk = 0; kk < 8; ++kk) {
            bf16x8 b[4];
#pragma unroll
            for (int n = 0; n < 4; ++n) {
                const int rr   = n * 16 + lg;
                const int gran = (kk * 4 + g) ^ swr;
                b[n] = *reinterpret_cast<const bf16x8*>(kbase + rr * D + gran * 8);
            }
#pragma unroll
            for (int mi = 0; mi < 4; ++mi)
#pragma unroll
                for (int n = 0; n < 4; ++n)
                    acc[mi][n] = __builtin_amdgcn_mfma_f32_16x16x32_bf16(
                        afrag[mi][kk], b[n], acc[mi][n], 0, 0, 0);
        }

        const int crow0 = colbase + t * BN;
        if (qrow0 == crow0)   // wave's 64-row block vs tile's 64-col block
            epilogue<true >(acc, m2, l2, qrow0, crow0, g, lg);
        else
            epilogue<false>(acc, m2, l2, qrow0, crow0, g, lg);

        __syncthreads();      // drains prefetch (vmcnt) + all waves done with ks[cur]
        cur ^= 1;
    }
#undef STAGE

    // merge (m,l) across the 16-lane column group
#pragma unroll
    for (int s = 0; s < 16; ++s) {
        float m = m2[s], l = l2[s];
#pragma unroll
        for (int off = 1; off < 16; off <<= 1) {
            float mo = __shfl_xor(m, off);
            float lo = __shfl_xor(l, off);
            float mm = fmaxf(m, mo);
            l = l * fexp2(m - mm) + lo * fexp2(mo - mm);
            m = mm;
        }
        m2[s] = m; l2[s] = l;
    }
    if (lg == 0) {
#pragma unroll
        for (int mi = 0; mi < 4; ++mi)
#pragma unroll
            for (int j = 0; j < 4; ++j) {
                int r = qrow0 + mi * 16 + g * 4 + j;
                int s = mi * 4 + j;
                float* p = part + (size_t)(r * NSPLIT + split) * 2;
                p[0] = m2[s]; p[1] = l2[s];
            }
    }
}

// ---------------- stage 3: per-row combine + deterministic sum ----------------
__global__ void reduce_kernel(const float* __restrict__ part,
                              const float* __restrict__ tnat,
                              float* __restrict__ bsum) {
    int r = blockIdx.x * 256 + threadIdx.x;
    float m = -1e30f, l = 0.f;
#pragma unroll
    for (int s = 0; s < NSPLIT; ++s) {
        const float* p = part + (size_t)(r * NSPLIT + s) * 2;
        float ms = p[0], lv = p[1];
        float mm = fmaxf(m, ms);
        l = l * fexp2(m - mm) + lv * fexp2(ms - mm);
        m = mm;
    }
    float v = LN2 * (m + __log2f(l)) - tnat[r];   // nll for this row
#pragma unroll
    for (int off = 1; off < 64; off <<= 1) v += __shfl_xor(v, off);
    __shared__ float ws4[4];
    int lane = threadIdx.x & 63, wid = threadIdx.x >> 6;
    if (lane == 0) ws4[wid] = v;
    __syncthreads();
    if (threadIdx.x == 0)
        bsum[blockIdx.x] = ws4[0] + ws4[1] + ws4[2] + ws4[3];
}

__global__ void final_kernel(const float* __restrict__ bsum,
                             float* __restrict__ out) {
    float v = bsum[threadIdx.x];   // 64 threads, 64 block sums
#pragma unroll
    for (int off = 1; off < 64; off <<= 1) v += __shfl_xor(v, off);
    if (threadIdx.x == 0) out[0] = v * (1.0f / (float)N_TOT);
}

extern "C" void kernel_launch(void* const* d_in, const int* in_sizes, int n_in,
                              void* d_out, int out_size, void* d_ws, size_t ws_size,
                              hipStream_t stream) {
    const float* z1 = (const float*)d_in[0];
    const float* z2 = (const float*)d_in[1];
    const float* ls = (const float*)d_in[2];
    float* out = (float*)d_out;

    ushort* zbs  = (ushort*)d_ws;                                        // 8 MB
    float*  part = (float*)((char*)d_ws + (size_t)N_TOT * D * 2);        // 1 MB
    float*  tnat = (float*)((char*)part + (size_t)N_TOT * NSPLIT * 2 * sizeof(float));
    float*  bsum = (float*)((char*)tnat + (size_t)N_TOT * sizeof(float));

    convert_kernel<<<(N_TOT * D / 4 + 255) / 256, 256, 0, stream>>>(z1, z2, ls, zbs);
    target_kernel<<<N_TOT / 4, 256, 0, stream>>>(z1, z2, ls, tnat);
    dim3 grid(N_TOT / BM, NSPLIT);
    infonce_main<<<grid, 256, 0, stream>>>(zbs, part);
    reduce_kernel<<<N_TOT / 256, 256, 0, stream>>>(part, tnat, bsum);
    final_kernel<<<1, 64, 0, stream>>>(bsum, out);
}

// Round 4
// 135.209 us; speedup vs baseline: 1.6444x; 1.6444x over previous
//
#include <hip/hip_runtime.h>
#include <hip/hip_bf16.h>

#define N_TOT 16384
#define B_HALF 8192
#define D 256
#define NGRAN 32                          // 16B granules per row (D/8)
#define BN 32                             // cols per tile
#define NSPLIT 8
#define COLS_PER_SPLIT (N_TOT / NSPLIT)   // 2048
#define NTILES (COLS_PER_SPLIT / BN)      // 64
#define BM 256                            // rows per block = 4 waves * 64

#define LOG2E 1.4426950408889634f
#define LN2   0.6931471805599453f

typedef short bf16x8 __attribute__((ext_vector_type(8)));
typedef float f32x4 __attribute__((ext_vector_type(4)));

__device__ __forceinline__ float fexp2(float x) {
#if __has_builtin(__builtin_amdgcn_exp2f)
    return __builtin_amdgcn_exp2f(x);
#else
    return __expf(x * LN2);
#endif
}

__device__ __forceinline__ ushort f2bf(float x) {
    uint32_t u = __float_as_uint(x);
    uint32_t r = u + 0x7FFFu + ((u >> 16) & 1u);   // RNE; inputs finite
    return (ushort)(r >> 16);
}

// ---------------- stage 1: fp32 -> prescaled bf16, TRANSPOSED granule layout --
// zt granule (c, r) at elem offset (c*N_TOT + r)*8 holds z[r][c*8 .. c*8+7] * s
// so zt_i . zt_j = log2-domain logit. Writes fully coalesced.
__global__ void convert_kernel(const float* __restrict__ z1,
                               const float* __restrict__ z2,
                               const float* __restrict__ lsp,
                               ushort* __restrict__ zt) {
    const float scale = fminf(__expf(lsp[0]), 100.0f);
    const float s = __fsqrt_rn(scale * LOG2E);
    int T = blockIdx.x * blockDim.x + threadIdx.x;   // T = c*N_TOT + r
    const int c = T >> 14;                            // /N_TOT
    const int r = T & (N_TOT - 1);
    const int half_elems = B_HALF * D;
    int e = r * D + c * 8;
    const float* src = (e < half_elems) ? (z1 + e) : (z2 + (e - half_elems));
    float4 f0 = *reinterpret_cast<const float4*>(src);
    float4 f1 = *reinterpret_cast<const float4*>(src + 4);
    ushort o[8];
    o[0] = f2bf(f0.x * s); o[1] = f2bf(f0.y * s); o[2] = f2bf(f0.z * s); o[3] = f2bf(f0.w * s);
    o[4] = f2bf(f1.x * s); o[5] = f2bf(f1.y * s); o[6] = f2bf(f1.z * s); o[7] = f2bf(f1.w * s);
    *reinterpret_cast<bf16x8*>(zt + (size_t)T * 8) = *reinterpret_cast<bf16x8*>(o);
}

// ---------------- stage 1b: exact fp32 target logits ----------------
__global__ void target_kernel(const float* __restrict__ z1,
                              const float* __restrict__ z2,
                              const float* __restrict__ lsp,
                              float* __restrict__ tnat) {
    const int r    = blockIdx.x * 4 + (threadIdx.x >> 6);
    const int lane = threadIdx.x & 63;
    const float* zr = (r < B_HALF) ? (z1 + (size_t)r * D) : (z2 + (size_t)(r - B_HALF) * D);
    const float* zp = (r < B_HALF) ? (z2 + (size_t)r * D) : (z1 + (size_t)(r - B_HALF) * D);
    float4 a = *reinterpret_cast<const float4*>(zr + lane * 4);
    float4 b = *reinterpret_cast<const float4*>(zp + lane * 4);
    float d = a.x * b.x + a.y * b.y + a.z * b.z + a.w * b.w;
#pragma unroll
    for (int off = 1; off < 64; off <<= 1) d += __shfl_xor(d, off);
    if (lane == 0) {
        const float scale = fminf(__expf(lsp[0]), 100.0f);
        tnat[r] = scale * d;
    }
}

// ---------------- epilogue helper ----------------
template<bool MASKD>
__device__ __forceinline__ void epilogue(const f32x4 (&acc)[4][2],
                                         float (&m2)[16], float (&l2)[16],
                                         int qrow0, int crow0, int g, int lg) {
#pragma unroll
    for (int mi = 0; mi < 4; ++mi) {
#pragma unroll
        for (int j = 0; j < 4; ++j) {
            const int slot = mi * 4 + j;
            float v0 = acc[mi][0][j], v1 = acc[mi][1][j];
            if (MASKD) {
                const int r  = qrow0 + mi * 16 + g * 4 + j;
                const int c0 = crow0 + lg;
                if (c0      == r) v0 = -1e30f;
                if (c0 + 16 == r) v1 = -1e30f;
            }
            const float m_old = m2[slot];
            float m_new = fmaxf(fmaxf(v0, v1), m_old);
            float lr = l2[slot] * fexp2(m_old - m_new);
            lr += fexp2(v0 - m_new);
            lr += fexp2(v1 - m_new);
            m2[slot] = m_new;
            l2[slot] = lr;
        }
    }
}

// ---------------- stage 2: flash-style LSE sweep, M-rep=4, dbuf LDS ----------------
__global__ __launch_bounds__(256)
__attribute__((amdgpu_waves_per_eu(2, 2)))
void infonce_main(const ushort* __restrict__ zt,
                  float* __restrict__ part) {
    // transposed tile: granule-column c (0..31) x row r (0..31), 16B entries
    __shared__ ushort ks[2][BN * D];   // 2 x 16 KB, linear

    const int tid  = threadIdx.x;
    const int wid  = tid >> 6;
    const int lane = tid & 63;
    const int g    = lane >> 4;     // 0..3
    const int lg   = lane & 15;     // 0..15
    const int qrow0   = blockIdx.x * BM + wid * 64;
    const int split   = blockIdx.y;
    const int colbase = split * COLS_PER_SPLIT;

    // A fragments: 4 M-frags x 8 K-frags, register-resident (128 VGPR)
    // afrag[mi][kk] = z[qrow0+mi*16+lg][kk*32 + g*8 ..] = zt granule (kk*4+g, row)
    bf16x8 afrag[4][8];
#pragma unroll
    for (int kk = 0; kk < 8; ++kk) {
        const ushort* ap = zt + ((size_t)(kk * 4 + g) * N_TOT + qrow0 + lg) * 8;
#pragma unroll
        for (int mi = 0; mi < 4; ++mi)
            afrag[mi][kk] = *reinterpret_cast<const bf16x8*>(ap + (size_t)mi * 16 * 8);
    }

    float m2[16], l2[16];
#pragma unroll
    for (int s = 0; s < 16; ++s) { m2[s] = -1e30f; l2[s] = 0.0f; }

    // staging: chunk = it*256 + tid ; c = chunk>>5 ; r = chunk&31 ; all linear
    const int wbase = tid & ~63;               // wave-uniform LDS base (chunks)
    const int csrc  = tid >> 5;                // it-invariant part of c (0..7)
    const int rsrc  = tid & 31;
    const ushort* src0 = zt + ((size_t)csrc * N_TOT + rsrc) * 8;

#define STAGE(buf, t)                                                               \
    {                                                                               \
        const ushort* srcT = src0 + (size_t)(colbase + (t) * BN) * 8;               \
        _Pragma("unroll")                                                           \
        for (int it = 0; it < 4; ++it)                                              \
            __builtin_amdgcn_global_load_lds(                                       \
                (const __attribute__((address_space(1))) void*)(srcT + (size_t)it * 8 * N_TOT * 8), \
                (__attribute__((address_space(3))) void*)&ks[buf][(it * 256 + wbase) * 8], \
                16, 0, 0);                                                          \
    }

    STAGE(0, 0);
    __syncthreads();
    int cur = 0;

    for (int t = 0; t < NTILES; ++t) {
        if (t + 1 < NTILES) STAGE(cur ^ 1, t + 1);   // prefetch next tile

        f32x4 acc[4][2];
#pragma unroll
        for (int mi = 0; mi < 4; ++mi)
#pragma unroll
            for (int n = 0; n < 2; ++n) acc[mi][n] = (f32x4){0.f, 0.f, 0.f, 0.f};

        const ushort* kbase = &ks[cur][0];
#pragma unroll
        for (int kk = 0; kk < 8; ++kk) {
            bf16x8 b[2];
#pragma unroll
            for (int n = 0; n < 2; ++n) {
                // granule-column c = kk*4+g, row = n*16+lg  -> contiguous per 16 lanes
                b[n] = *reinterpret_cast<const bf16x8*>(
                    kbase + (((kk * 4 + g) * BN) + n * 16 + lg) * 8);
            }
#pragma unroll
            for (int mi = 0; mi < 4; ++mi)
#pragma unroll
                for (int n = 0; n < 2; ++n)
                    acc[mi][n] = __builtin_amdgcn_mfma_f32_16x16x32_bf16(
                        afrag[mi][kk], b[n], acc[mi][n], 0, 0, 0);
        }

        const int crow0 = colbase + t * BN;
        if ((crow0 >> 6) == (qrow0 >> 6))   // 32-col tile inside wave's 64-row block?
            epilogue<true >(acc, m2, l2, qrow0, crow0, g, lg);
        else
            epilogue<false>(acc, m2, l2, qrow0, crow0, g, lg);

        __syncthreads();      // drains prefetch + all waves done with ks[cur]
        cur ^= 1;
    }
#undef STAGE

    // merge (m,l) across the 16-lane column group
#pragma unroll
    for (int s = 0; s < 16; ++s) {
        float m = m2[s], l = l2[s];
#pragma unroll
        for (int off = 1; off < 16; off <<= 1) {
            float mo = __shfl_xor(m, off);
            float lo = __shfl_xor(l, off);
            float mm = fmaxf(m, mo);
            l = l * fexp2(m - mm) + lo * fexp2(mo - mm);
            m = mm;
        }
        m2[s] = m; l2[s] = l;
    }
    if (lg == 0) {
#pragma unroll
        for (int mi = 0; mi < 4; ++mi)
#pragma unroll
            for (int j = 0; j < 4; ++j) {
                int r = qrow0 + mi * 16 + g * 4 + j;
                int s = mi * 4 + j;
                float* p = part + (size_t)(r * NSPLIT + split) * 2;
                p[0] = m2[s]; p[1] = l2[s];
            }
    }
}

// ---------------- stage 3: per-row combine + deterministic sum ----------------
__global__ void reduce_kernel(const float* __restrict__ part,
                              const float* __restrict__ tnat,
                              float* __restrict__ bsum) {
    int r = blockIdx.x * 256 + threadIdx.x;
    float m = -1e30f, l = 0.f;
#pragma unroll
    for (int s = 0; s < NSPLIT; ++s) {
        const float* p = part + (size_t)(r * NSPLIT + s) * 2;
        float ms = p[0], lv = p[1];
        float mm = fmaxf(m, ms);
        l = l * fexp2(m - mm) + lv * fexp2(ms - mm);
        m = mm;
    }
    float v = LN2 * (m + __log2f(l)) - tnat[r];   // nll for this row
#pragma unroll
    for (int off = 1; off < 64; off <<= 1) v += __shfl_xor(v, off);
    __shared__ float ws4[4];
    int lane = threadIdx.x & 63, wid = threadIdx.x >> 6;
    if (lane == 0) ws4[wid] = v;
    __syncthreads();
    if (threadIdx.x == 0)
        bsum[blockIdx.x] = ws4[0] + ws4[1] + ws4[2] + ws4[3];
}

__global__ void final_kernel(const float* __restrict__ bsum,
                             float* __restrict__ out) {
    float v = bsum[threadIdx.x];   // 64 threads, 64 block sums
#pragma unroll
    for (int off = 1; off < 64; off <<= 1) v += __shfl_xor(v, off);
    if (threadIdx.x == 0) out[0] = v * (1.0f / (float)N_TOT);
}

extern "C" void kernel_launch(void* const* d_in, const int* in_sizes, int n_in,
                              void* d_out, int out_size, void* d_ws, size_t ws_size,
                              hipStream_t stream) {
    const float* z1 = (const float*)d_in[0];
    const float* z2 = (const float*)d_in[1];
    const float* ls = (const float*)d_in[2];
    float* out = (float*)d_out;

    ushort* zt   = (ushort*)d_ws;                                        // 8 MB
    float*  part = (float*)((char*)d_ws + (size_t)N_TOT * D * 2);        // 1 MB
    float*  tnat = (float*)((char*)part + (size_t)N_TOT * NSPLIT * 2 * sizeof(float));
    float*  bsum = (float*)((char*)tnat + (size_t)N_TOT * sizeof(float));

    convert_kernel<<<(N_TOT * NGRAN) / 256, 256, 0, stream>>>(z1, z2, ls, zt);
    target_kernel<<<N_TOT / 4, 256, 0, stream>>>(z1, z2, ls, tnat);
    dim3 grid(N_TOT / BM, NSPLIT);
    infonce_main<<<grid, 256, 0, stream>>>(zt, part);
    reduce_kernel<<<N_TOT / 256, 256, 0, stream>>>(part, tnat, bsum);
    final_kernel<<<1, 64, 0, stream>>>(bsum, out);
}